// Round 15
// baseline (209.694 us; speedup 1.0000x reference)
//
#include <hip/hip_runtime.h>
#include <hip/hip_bf16.h>

#define N_NODES 50000
#define N_EDGES 800000
#define NB1 400       // k1 bucketing blocks
#define CH  2000      // edges per k1 block (NB1*CH == N_EDGES)
#define NBKT 196      // MSD buckets = key>>8
#define CAP 8192      // slots per bucket (mean ~4082, +64 sigma headroom)
#define SORT_MAX 6144 // k2 LDS sort capacity per bucket (+32 sigma)

typedef unsigned short ushort_t;
typedef unsigned long long u64;
typedef __attribute__((ext_vector_type(8))) short bf16x8;
typedef __attribute__((ext_vector_type(4))) float f32x4;

// ---------------- workspace layout (4-byte word offsets) ----------------
// gcur cursors are 64B-line padded: col bucket b -> gcur[b*16], row -> gcur[(196+b)*16]
constexpr int GCUR_O  = 0;           // uint[782*16] padded cursors (50 KB)
constexpr int DIS_O   = 12544;       // float[50000]
constexpr int OFF_O   = 62592;       // int[50001]
constexpr int CSLOT_O = 112640;      // uint[196*8192] col buckets (bf16w<<16 | row16)
constexpr int CDIG_O  = 1718272;     // u8[196*8192] col digit sideband (col&255)
constexpr int RSLOT_O = 2119680;     // uint[196*8192] row buckets (w24 | row8); T1S after k2
constexpr int RW_O    = 3725312;     // uint[800000] CSR payload (bf16w | row16)
constexpr int ABUF_O  = 4525312;     // uint[50000*96] A=[x|tx1|tx2] bf16x2
constexpr int PBUF_O  = 9325312;     // ushort[24576] packed B
constexpr int XS_O    = 9337600;     // uint[50000*32] xs = dis*x (own region, no alias)
constexpr int T1S_O   = RSLOT_O;     // uint[50000*32] dis*tx1 (safe: rslot dead after k2)
// total ~10.94M words = 43.8 MB

__device__ __forceinline__ ushort_t f32_to_bf16(float f) {
    unsigned u = __float_as_uint(f);
    u += 0x7fffu + ((u >> 16) & 1u);   // round-to-nearest-even
    return (ushort_t)(u >> 16);
}
__device__ __forceinline__ float bflo(unsigned u) { return __uint_as_float(u << 16); }
__device__ __forceinline__ float bfhi(unsigned u) { return __uint_as_float(u & 0xffff0000u); }
__device__ __forceinline__ unsigned packbf2(float a, float b) {
    return (unsigned)f32_to_bf16(a) | ((unsigned)f32_to_bf16(b) << 16);
}
__device__ __forceinline__ float fsigmoid(float x) { return 1.f / (1.f + __expf(-x)); }
__device__ __forceinline__ float ftanh(float x) {
    x = fminf(15.f, fmaxf(-15.f, x));
    float e = __expf(2.f * x);
    return (e - 1.f) / (e + 1.f);
}

// inclusive shuffle-scan of 256 values held by threads t<256 (waves 0..3)
__device__ __forceinline__ unsigned block_scan256_incl(unsigned v, int t, unsigned* wsum) {
    int lane = t & 63;
    unsigned sc = v;
#pragma unroll
    for (int o = 1; o < 64; o <<= 1) {
        unsigned u = __shfl_up(sc, o, 64);
        if (lane >= o) sc += u;
    }
    if (t < 256 && lane == 63) wsum[t >> 6] = sc;
    __syncthreads();
    if (t < 256) {
        int wid = t >> 6;
        unsigned off = 0;
#pragma unroll
        for (int wv = 0; wv < 3; ++wv) if (wv < wid) off += wsum[wv];
        sc += off;
    }
    __syncthreads();   // wsum free for reuse
    return sc;
}

// ---- k1: dual MSD bucketing with LDS order map -> run-coalesced bucket writes ----
// cslot compressed to 4B payload + 1B digit sideband (w already bf16 in rw path).
__global__ __launch_bounds__(512) void k1(
    const int* __restrict__ ei, const float* __restrict__ ew,
    const float* __restrict__ Wxz, const float* __restrict__ Wxh,
    unsigned* __restrict__ gcur, unsigned* __restrict__ cslot,
    unsigned char* __restrict__ cdig, unsigned* __restrict__ rslot,
    ushort_t* __restrict__ pbuf) {
    int bid = blockIdx.x, t = threadIdx.x;
    __shared__ u64 pC[CH];                       // 16 KB payloads in load order
    __shared__ ushort_t ordC[CH], ordR[CH];      // 8 KB sorted_pos -> load idx
    __shared__ unsigned char digC[CH], digR[CH]; // 4 KB digit at sorted pos
    __shared__ unsigned hc[256], hr[256], scC[256], scR[256], bc[256], br[256];
    __shared__ unsigned wsum[8];
    if (bid < NB1) {
        if (t < 256) { hc[t] = 0; hr[t] = 0; }
        __syncthreads();
        int e0 = bid * CH;
        for (int i = t; i < CH; i += 512) {      // pass 1: stage + histograms
            unsigned r = (unsigned)ei[e0 + i];
            unsigned c = (unsigned)ei[N_EDGES + e0 + i];
            unsigned w = __float_as_uint(ew[e0 + i]);
            unsigned dc = c >> 8;
            pC[i] = ((u64)w << 32) | (dc << 24) | ((c & 255u) << 16) | (r & 0xFFFFu);
            atomicAdd(&hc[dc], 1u);
            atomicAdd(&hr[r >> 8], 1u);
        }
        __syncthreads();
        if (t < NBKT) {                          // global slot allocation (padded lines)
            bc[t] = atomicAdd(&gcur[t * 16], hc[t]);
            br[t] = atomicAdd(&gcur[(NBKT + t) * 16], hr[t]);
        }
        unsigned vC = (t < 256) ? hc[t] : 0u;
        unsigned vR = (t < 256) ? hr[t] : 0u;
        unsigned iC = block_scan256_incl(vC, t, wsum);
        unsigned iR = block_scan256_incl(vR, t, wsum);
        if (t < 256) {
            scC[t] = iC - vC;                    // exclusive prefixes
            scR[t] = iR - vR;
            hc[t] = 0; hr[t] = 0;                // reuse as local cursors
        }
        __syncthreads();
        for (int i = t; i < CH; i += 512) {      // pass 2: build order maps
            u64 p = pC[i];
            unsigned dc = (unsigned)(p >> 24) & 255u;
            unsigned pc = scC[dc] + atomicAdd(&hc[dc], 1u);
            ordC[pc] = (ushort_t)i;
            digC[pc] = (unsigned char)dc;
            unsigned r = (unsigned)p & 0xFFFFu;
            unsigned dr = r >> 8;
            unsigned pr = scR[dr] + atomicAdd(&hr[dr], 1u);
            ordR[pr] = (ushort_t)i;
            digR[pr] = (unsigned char)dr;
        }
        __syncthreads();
        for (int i = t; i < CH; i += 512) {      // pass 3: run-coalesced emission
            unsigned dc = digC[i];
            u64 p = pC[ordC[i]];
            unsigned slotC = bc[dc] + (unsigned)i - scC[dc];
            if (slotC < CAP) {
                float w = __uint_as_float((unsigned)(p >> 32));
                cslot[(size_t)dc * CAP + slotC] =
                    ((unsigned)f32_to_bf16(w) << 16) | ((unsigned)p & 0xFFFFu);
                cdig[(size_t)dc * CAP + slotC] = (unsigned char)((p >> 16) & 255u);
            }
            unsigned dr = digR[i];
            u64 q = pC[ordR[i]];
            unsigned slotR = br[dr] + (unsigned)i - scR[dr];
            if (slotR < CAP)
                rslot[(size_t)dr * CAP + slotR] =
                    ((unsigned)(q >> 32) & 0xFFFFFF00u) | ((unsigned)q & 255u);
        }
    } else {                                     // pack B into MFMA fragment order
        for (int idx = t; idx < 24576; idx += 512) {
            int k = idx >> 7, n = idx & 127;
            float v = (n < 64) ? Wxz[k * 64 + n] : Wxh[k * 64 + (n - 64)];
            int c = n >> 4, s = k >> 5, l = (((k >> 3) & 3) << 4) | (n & 15), j = k & 7;
            pbuf[((c * 6 + s) * 64 + l) * 8 + j] = f32_to_bf16(v);
        }
    }
}

// ---- k2: blocks [0,196): per-bucket sort -> off + coalesced u32 rw stream-out
//          blocks [196,392): deg (LDS fadd) -> dis, x-cast + xs ----
__global__ __launch_bounds__(512) void k2(
    const float* __restrict__ x, const unsigned* __restrict__ gcur,
    const unsigned* __restrict__ cslot, const unsigned char* __restrict__ cdig,
    const unsigned* __restrict__ rslot,
    float* __restrict__ dis, int* __restrict__ off, unsigned* __restrict__ rw,
    unsigned* __restrict__ abuf, unsigned* __restrict__ xs) {
    int bid = blockIdx.x, t = threadIdx.x;
    __shared__ unsigned srt[SORT_MAX];           // 24 KB bucket-sorted u32 payloads
    __shared__ unsigned hist[256], hsc[256], cur[256], gs[256];
    __shared__ unsigned wsum[8];
    __shared__ float facc[256];

    if (bid < NBKT) {
        // ---- phase A: sort col bucket bid by digit -> off + coalesced rw ----
        unsigned szv = (t < NBKT) ? gcur[t * 16] : 0u;
        unsigned inc = block_scan256_incl(szv, t, wsum);
        if (t < 256) gs[t] = inc - szv;          // exclusive prefix of bucket sizes
        if (t < 256) hist[t] = 0;
        __syncthreads();
        unsigned szb = gcur[bid * 16];
        unsigned sz = min(szb, (unsigned)SORT_MAX);
        unsigned base = gs[bid];
        const unsigned char* dg = cdig + (size_t)bid * CAP;
        const unsigned* cs = cslot + (size_t)bid * CAP;
        for (unsigned i = t; i < sz; i += 512)   // read 1 (coalesced): digit hist
            atomicAdd(&hist[dg[i]], 1u);
        __syncthreads();
        unsigned h0 = (t < 256) ? hist[t] : 0u;
        unsigned hinc = block_scan256_incl(h0, t, wsum);
        if (t < 256) {
            hsc[t] = hinc - h0;                  // exclusive
            cur[t] = 0u;
            int c = bid * 256 + t;
            if (c <= N_NODES) off[c] = (int)(base + hsc[t]);
        }
        __syncthreads();
        for (unsigned i = t; i < sz; i += 512) { // read 2 (L2-hot): LDS scatter
            unsigned d = dg[i];
            unsigned p = hsc[d] + atomicAdd(&cur[d], 1u);
            srt[p] = cs[i];
        }
        __syncthreads();
        for (unsigned i = t; i < sz; i += 512)   // coalesced rw stream-out (no convert)
            rw[base + i] = srt[i];
    } else {
        // ---- phase B: deg for rows [b*256,+256), dis, x-cast + xs ----
        int b = bid - NBKT;
        if (t < 256) facc[t] = 0.f;
        __syncthreads();
        unsigned szr = min(gcur[(NBKT + b) * 16], (unsigned)CAP);
        const unsigned* rs = rslot + (size_t)b * CAP;
        for (unsigned i = t; i < szr; i += 512)
            atomicAdd(&facc[rs[i] & 255u], __uint_as_float(rs[i] & 0xFFFFFF00u));
        __syncthreads();
        if (t < 256) {
            float d = facc[t];
            float r = d > 0.f ? rsqrtf(d) : 0.f;
            facc[t] = r;
            int n = b * 256 + t;
            if (n < N_NODES) dis[n] = r;
        }
        __syncthreads();
        for (int idx = t; idx < 8192; idx += 512) {   // x-cast + xs from one x load
            int nl = idx >> 5, q = idx & 31;
            int n = b * 256 + nl;
            if (n < N_NODES) {
                float2 xv = ((const float2*)x)[n * 32 + q];
                float r = facc[nl];
                abuf[n * 96 + q] = packbf2(xv.x, xv.y);       // plain x bf16
                xs[n * 32 + q] = packbf2(r * xv.x, r * xv.y); // dis*x bf16
            }
        }
    }
}

// ---- prop: one wave per node; halves handle alternating edges; u32 rw ----
// mode 0: tx1 = -dis*sum(w*xs[row]); write abuf tx1 + t1s = dis*tx1
// mode 1: tx2 = 2*(-dis*sum(w*t1s[row])) - x(fp32); write abuf tx2
__global__ __launch_bounds__(256) void k_prop(
    const int* __restrict__ off, const unsigned* __restrict__ rw,
    const unsigned* __restrict__ xsrc, const float* __restrict__ dis,
    const float* __restrict__ xf, unsigned* __restrict__ abuf,
    unsigned* __restrict__ t1s, int mode) {
    int node = (blockIdx.x * 256 + threadIdx.x) >> 6;
    if (node >= N_NODES) return;
    int lane = threadIdx.x & 63, h = lane >> 5, q = lane & 31;
    int b = off[node], end = off[node + 1];
    float di = dis[node];
    float acc0 = 0.f, acc1 = 0.f;
    for (; b + 7 < end; b += 8) {
        unsigned v0 = rw[b + h], v1 = rw[b + h + 2], v2 = rw[b + h + 4], v3 = rw[b + h + 6];
        unsigned u0 = xsrc[(v0 & 0xFFFFu) * 32 + q];
        unsigned u1 = xsrc[(v1 & 0xFFFFu) * 32 + q];
        unsigned u2 = xsrc[(v2 & 0xFFFFu) * 32 + q];
        unsigned u3 = xsrc[(v3 & 0xFFFFu) * 32 + q];
        float a0 = bfhi(v0), a1 = bfhi(v1), a2 = bfhi(v2), a3 = bfhi(v3);
        acc0 += a0 * bflo(u0) + a1 * bflo(u1) + a2 * bflo(u2) + a3 * bflo(u3);
        acc1 += a0 * bfhi(u0) + a1 * bfhi(u1) + a2 * bfhi(u2) + a3 * bfhi(u3);
    }
    for (; b + 1 < end; b += 2) {
        unsigned v = rw[b + h];
        unsigned u = xsrc[(v & 0xFFFFu) * 32 + q];
        float a = bfhi(v);
        acc0 += a * bflo(u); acc1 += a * bfhi(u);
    }
    if (b < end && h == 0) {
        unsigned v = rw[b];
        unsigned u = xsrc[(v & 0xFFFFu) * 32 + q];
        float a = bfhi(v);
        acc0 += a * bflo(u); acc1 += a * bfhi(u);
    }
    acc0 += __shfl_xor(acc0, 32, 64);
    acc1 += __shfl_xor(acc1, 32, 64);
    if (h == 0) {
        float t0 = -di * acc0, t1v = -di * acc1;
        if (mode == 0) {
            abuf[node * 96 + 32 + q] = packbf2(t0, t1v);
            t1s[node * 32 + q] = packbf2(di * t0, di * t1v);
        } else {
            float2 xv = ((const float2*)xf)[node * 32 + q];
            abuf[node * 96 + 64 + q] = packbf2(2.f * t0 - xv.x, 2.f * t1v - xv.y);
        }
    }
}

// ---- MFMA GEMM [50048x192]@[192x128] + GRU combine + head (2 tiles/block) ----
__global__ __launch_bounds__(256) void k_gemm(
    const ushort_t* __restrict__ ab, const ushort_t* __restrict__ pbuf,
    const float* __restrict__ bxz, const float* __restrict__ bhz,
    const float* __restrict__ bxh, const float* __restrict__ bhh,
    const float* __restrict__ Wlin, const float* __restrict__ blin,
    float2* __restrict__ out) {
    __shared__ ushort_t bsh[24576];
    int tid = threadIdx.x;
    {
        uint4* s4 = (uint4*)bsh;
        const uint4* g4 = (const uint4*)pbuf;
        for (int i = tid; i < 3072; i += 256) s4[i] = g4[i];
    }
    __syncthreads();

    int wave = tid >> 6, lane = tid & 63;
    int quad = lane >> 4, m = lane & 15;

    float bzv[4], bhv[4], wl0[4], wl1[4];
#pragma unroll
    for (int c = 0; c < 4; ++c) {
        int col = c * 16 + m;
        bzv[c] = bxz[col] + bhz[col];
        bhv[c] = bxh[col] + bhh[col];
        wl0[c] = Wlin[2 * col];
        wl1[c] = Wlin[2 * col + 1];
    }
    float bl0 = blin[0], bl1 = blin[1];

    for (int tile = 0; tile < 2; ++tile) {
        int n0 = (blockIdx.x * 2 + tile) * 64;
        int arow = n0 + wave * 16 + m;
        const ushort_t* ap = ab + (size_t)arow * 192 + quad * 8;

        f32x4 acc[8];
#pragma unroll
        for (int c = 0; c < 8; ++c) acc[c] = (f32x4){0.f, 0.f, 0.f, 0.f};
#pragma unroll
        for (int s = 0; s < 6; ++s) {
            bf16x8 af = *(const bf16x8*)(ap + s * 32);
#pragma unroll
            for (int c = 0; c < 8; ++c) {
                bf16x8 bfr = *(const bf16x8*)(bsh + ((c * 6 + s) * 64 + lane) * 8);
                acc[c] = __builtin_amdgcn_mfma_f32_16x16x32_bf16(af, bfr, acc[c], 0, 0, 0);
            }
        }
#pragma unroll
        for (int i = 0; i < 4; ++i) {
            float p0 = 0.f, p1 = 0.f;
#pragma unroll
            for (int c = 0; c < 4; ++c) {
                float z  = fsigmoid(acc[c][i] + bzv[c]);
                float ht = ftanh(acc[c + 4][i] + bhv[c]);
                float t  = ftanh((1.f - z) * ht);
                p0 += t * wl0[c];
                p1 += t * wl1[c];
            }
            for (int o = 1; o <= 8; o <<= 1) {
                p0 += __shfl_xor(p0, o, 64);
                p1 += __shfl_xor(p1, o, 64);
            }
            int g = n0 + wave * 16 + quad * 4 + i;
            if (m == 0 && g < N_NODES)
                out[g] = make_float2(fsigmoid(p0 + bl0), fsigmoid(p1 + bl1));
        }
    }
}

extern "C" void kernel_launch(void* const* d_in, const int* in_sizes, int n_in,
                              void* d_out, int out_size, void* d_ws, size_t ws_size,
                              hipStream_t stream) {
    const float* x    = (const float*)d_in[0];
    const int*   ei   = (const int*)d_in[1];
    const float* ew   = (const float*)d_in[2];
    const float* Wxz  = (const float*)d_in[3];
    const float* bxz  = (const float*)d_in[4];
    const float* bhz  = (const float*)d_in[6];
    const float* Wxh  = (const float*)d_in[11];
    const float* bxh  = (const float*)d_in[12];
    const float* bhh  = (const float*)d_in[14];
    const float* Wlin = (const float*)d_in[15];
    const float* blin = (const float*)d_in[16];

    float*         ws    = (float*)d_ws;
    unsigned*      gcur  = (unsigned*)(ws + GCUR_O);
    float*         dis   = ws + DIS_O;
    int*           off   = (int*)(ws + OFF_O);
    unsigned*      cslot = (unsigned*)(ws + CSLOT_O);
    unsigned char* cdig  = (unsigned char*)(ws + CDIG_O);
    unsigned*      rslot = (unsigned*)(ws + RSLOT_O);
    unsigned*      rw    = (unsigned*)(ws + RW_O);
    unsigned*      abuf  = (unsigned*)(ws + ABUF_O);
    ushort_t*      pbuf  = (ushort_t*)(ws + PBUF_O);
    unsigned*      xs    = (unsigned*)(ws + XS_O);   // own region (no cslot alias)
    unsigned*      t1s   = (unsigned*)(ws + T1S_O);  // aliases rslot (safe)

    hipMemsetAsync(d_ws, 0, (size_t)(782 * 16) * 4, stream);   // padded cursors

    k1<<<NB1 + 1, 512, 0, stream>>>(ei, ew, Wxz, Wxh, gcur, cslot, cdig, rslot, pbuf);
    k2<<<2 * NBKT, 512, 0, stream>>>(x, gcur, cslot, cdig, rslot, dis, off, rw, abuf, xs);
    k_prop<<<12500, 256, 0, stream>>>(off, rw, xs, dis, x, abuf, t1s, 0);
    k_prop<<<12500, 256, 0, stream>>>(off, rw, t1s, dis, x, abuf, abuf, 1);
    k_gemm<<<391, 256, 0, stream>>>((const ushort_t*)abuf, pbuf, bxz, bhz, bxh, bhh,
                                    Wlin, blin, (float2*)d_out);
}

// Round 16
// 202.185 us; speedup vs baseline: 1.0371x; 1.0371x over previous
//
#include <hip/hip_runtime.h>
#include <hip/hip_bf16.h>

#define N_NODES 50000
#define N_EDGES 800000
#define NB1 400       // k1 bucketing blocks (R12 config — best verified)
#define CH  2000      // edges per k1 block (NB1*CH == N_EDGES)
#define NBKT 196      // MSD buckets = key>>8
#define CAP 8192      // slots per bucket (mean ~4082, +64 sigma headroom)
#define SORT_MAX 6144 // k2 LDS sort capacity per bucket (+32 sigma)

typedef unsigned short ushort_t;
typedef unsigned long long u64;
typedef __attribute__((ext_vector_type(8))) short bf16x8;
typedef __attribute__((ext_vector_type(4))) float f32x4;

// ---------------- workspace layout (4-byte word offsets) ----------------
constexpr int GCUR_O  = 0;           // uint[512]: [0,196) col cursors, [256,452) row cursors
constexpr int DIS_O   = 512;         // float[50000]
constexpr int OFF_O   = 50512;       // int[50001]
constexpr int CSLOT_O = 100544;      // u64[196*8192] col buckets (w | dc8 | col8 | row16)
constexpr int RSLOT_O = 3311808;     // uint[196*8192] row buckets (w24 | row8); T1S after k2
constexpr int RW_O    = 4917440;     // uint[800000] CSR payload (bf16 w | row16)
constexpr int ABUF_O  = 6517440;     // uint[50000*96] A=[x|tx1|tx2] bf16x2
constexpr int PBUF_O  = 11317440;    // ushort[24576] packed B
constexpr int XS_O    = 11329728;    // uint[50000*32] xs = dis*x (own region; must NOT alias cslot)
constexpr int T1S_O   = RSLOT_O;     // uint[50000*32] dis*tx1 (safe: rslot dead after k2)

__device__ __forceinline__ ushort_t f32_to_bf16(float f) {
    unsigned u = __float_as_uint(f);
    u += 0x7fffu + ((u >> 16) & 1u);   // round-to-nearest-even
    return (ushort_t)(u >> 16);
}
__device__ __forceinline__ float bflo(unsigned u) { return __uint_as_float(u << 16); }
__device__ __forceinline__ float bfhi(unsigned u) { return __uint_as_float(u & 0xffff0000u); }
__device__ __forceinline__ unsigned packbf2(float a, float b) {
    return (unsigned)f32_to_bf16(a) | ((unsigned)f32_to_bf16(b) << 16);
}
__device__ __forceinline__ float fsigmoid(float x) { return 1.f / (1.f + __expf(-x)); }
__device__ __forceinline__ float ftanh(float x) {
    x = fminf(15.f, fmaxf(-15.f, x));
    float e = __expf(2.f * x);
    return (e - 1.f) / (e + 1.f);
}

// inclusive shuffle-scan of 256 values held by threads t<256 (waves 0..3)
__device__ __forceinline__ unsigned block_scan256_incl(unsigned v, int t, unsigned* wsum) {
    int lane = t & 63;
    unsigned sc = v;
#pragma unroll
    for (int o = 1; o < 64; o <<= 1) {
        unsigned u = __shfl_up(sc, o, 64);
        if (lane >= o) sc += u;
    }
    if (t < 256 && lane == 63) wsum[t >> 6] = sc;
    __syncthreads();
    if (t < 256) {
        int wid = t >> 6;
        unsigned off = 0;
#pragma unroll
        for (int wv = 0; wv < 3; ++wv) if (wv < wid) off += wsum[wv];
        sc += off;
    }
    __syncthreads();   // wsum free for reuse
    return sc;
}

// ---- k1: dual MSD bucketing with LDS order map -> run-coalesced bucket writes ----
__global__ __launch_bounds__(512) void k1(
    const int* __restrict__ ei, const float* __restrict__ ew,
    const float* __restrict__ Wxz, const float* __restrict__ Wxh,
    unsigned* __restrict__ gcur, u64* __restrict__ cslot,
    unsigned* __restrict__ rslot, ushort_t* __restrict__ pbuf) {
    int bid = blockIdx.x, t = threadIdx.x;
    __shared__ u64 pC[CH];                       // 16 KB payloads in load order
    __shared__ ushort_t ordC[CH], ordR[CH];      // 8 KB sorted_pos -> load idx
    __shared__ unsigned char digC[CH], digR[CH]; // 4 KB digit at sorted pos
    __shared__ unsigned hc[256], hr[256], scC[256], scR[256], bc[256], br[256];
    __shared__ unsigned wsum[8];
    if (bid < NB1) {
        if (t < 256) { hc[t] = 0; hr[t] = 0; }
        __syncthreads();
        int e0 = bid * CH;
        for (int i = t; i < CH; i += 512) {      // pass 1: stage + histograms
            unsigned r = (unsigned)ei[e0 + i];
            unsigned c = (unsigned)ei[N_EDGES + e0 + i];
            unsigned w = __float_as_uint(ew[e0 + i]);
            unsigned dc = c >> 8;
            pC[i] = ((u64)w << 32) | (dc << 24) | ((c & 255u) << 16) | (r & 0xFFFFu);
            atomicAdd(&hc[dc], 1u);
            atomicAdd(&hr[r >> 8], 1u);
        }
        __syncthreads();
        if (t < NBKT) {                          // global slot allocation
            bc[t] = atomicAdd(&gcur[t], hc[t]);
            br[t] = atomicAdd(&gcur[256 + t], hr[t]);
        }
        unsigned vC = (t < 256) ? hc[t] : 0u;
        unsigned vR = (t < 256) ? hr[t] : 0u;
        unsigned iC = block_scan256_incl(vC, t, wsum);
        unsigned iR = block_scan256_incl(vR, t, wsum);
        if (t < 256) {
            scC[t] = iC - vC;                    // exclusive prefixes
            scR[t] = iR - vR;
            hc[t] = 0; hr[t] = 0;                // reuse as local cursors
        }
        __syncthreads();
        for (int i = t; i < CH; i += 512) {      // pass 2: build order maps
            u64 p = pC[i];
            unsigned dc = (unsigned)(p >> 24) & 255u;
            unsigned pc = scC[dc] + atomicAdd(&hc[dc], 1u);
            ordC[pc] = (ushort_t)i;
            digC[pc] = (unsigned char)dc;
            unsigned r = (unsigned)p & 0xFFFFu;
            unsigned dr = r >> 8;
            unsigned pr = scR[dr] + atomicAdd(&hr[dr], 1u);
            ordR[pr] = (ushort_t)i;
            digR[pr] = (unsigned char)dr;
        }
        __syncthreads();
        for (int i = t; i < CH; i += 512) {      // pass 3: run-coalesced emission
            unsigned dc = digC[i];
            u64 p = pC[ordC[i]];
            unsigned slotC = bc[dc] + (unsigned)i - scC[dc];
            if (slotC < CAP) cslot[(size_t)dc * CAP + slotC] = p;
            unsigned dr = digR[i];
            u64 q = pC[ordR[i]];
            unsigned slotR = br[dr] + (unsigned)i - scR[dr];
            if (slotR < CAP)
                rslot[(size_t)dr * CAP + slotR] =
                    ((unsigned)(q >> 32) & 0xFFFFFF00u) | ((unsigned)q & 255u);
        }
    } else {                                     // pack B into MFMA fragment order
        for (int idx = t; idx < 24576; idx += 512) {
            int k = idx >> 7, n = idx & 127;
            float v = (n < 64) ? Wxz[k * 64 + n] : Wxh[k * 64 + (n - 64)];
            int c = n >> 4, s = k >> 5, l = (((k >> 3) & 3) << 4) | (n & 15), j = k & 7;
            pbuf[((c * 6 + s) * 64 + l) * 8 + j] = f32_to_bf16(v);
        }
    }
}

// ---- k2: blocks [0,196): per-bucket sort -> off + COALESCED u32 rw stream-out
//          blocks [196,392): deg (LDS fadd) -> dis, x-cast + xs ----
__global__ __launch_bounds__(512) void k2(
    const float* __restrict__ x, const unsigned* __restrict__ gcur,
    const u64* __restrict__ cslot, const unsigned* __restrict__ rslot,
    float* __restrict__ dis, int* __restrict__ off, unsigned* __restrict__ rw,
    unsigned* __restrict__ abuf, unsigned* __restrict__ xs) {
    int bid = blockIdx.x, t = threadIdx.x;
    __shared__ u64 srt[SORT_MAX];                // 48 KB bucket-sorted payloads
    __shared__ unsigned hist[256], hsc[256], cur[256], gs[256];
    __shared__ unsigned wsum[8];
    __shared__ float facc[256];

    if (bid < NBKT) {
        // ---- phase A: sort col bucket bid by col&255 -> off + coalesced rw ----
        unsigned szv = (t < NBKT) ? gcur[t] : 0u;
        unsigned inc = block_scan256_incl(szv, t, wsum);
        if (t < 256) gs[t] = inc - szv;          // exclusive prefix of bucket sizes
        if (t < 256) hist[t] = 0;
        __syncthreads();
        unsigned szb = gcur[bid];
        unsigned sz = min(szb, (unsigned)SORT_MAX);
        unsigned base = gs[bid];
        const u64* cs = cslot + (size_t)bid * CAP;
        for (unsigned i = t; i < sz; i += 512)   // read 1 (coalesced): digit hist
            atomicAdd(&hist[((unsigned)cs[i] >> 16) & 255u], 1u);
        __syncthreads();
        unsigned h0 = (t < 256) ? hist[t] : 0u;
        unsigned hinc = block_scan256_incl(h0, t, wsum);
        if (t < 256) {
            hsc[t] = hinc - h0;                  // exclusive
            cur[t] = 0u;
            int c = bid * 256 + t;
            if (c <= N_NODES) off[c] = (int)(base + hsc[t]);
        }
        __syncthreads();
        for (unsigned i = t; i < sz; i += 512) { // read 2 (L2-hot): LDS scatter
            u64 v = cs[i];
            unsigned d = ((unsigned)v >> 16) & 255u;
            unsigned p = hsc[d] + atomicAdd(&cur[d], 1u);
            srt[p] = v;
        }
        __syncthreads();
        for (unsigned i = t; i < sz; i += 512) { // coalesced u32 rw stream-out
            u64 v = srt[i];
            float w = __uint_as_float((unsigned)(v >> 32));
            rw[base + i] = ((unsigned)f32_to_bf16(w) << 16) | ((unsigned)v & 0xFFFFu);
        }
    } else {
        // ---- phase B: deg for rows [b*256,+256), dis, x-cast + xs ----
        int b = bid - NBKT;
        if (t < 256) facc[t] = 0.f;
        __syncthreads();
        unsigned szr = min(gcur[256 + b], (unsigned)CAP);
        const unsigned* rs = rslot + (size_t)b * CAP;
        for (unsigned i = t; i < szr; i += 512)
            atomicAdd(&facc[rs[i] & 255u], __uint_as_float(rs[i] & 0xFFFFFF00u));
        __syncthreads();
        if (t < 256) {
            float d = facc[t];
            float r = d > 0.f ? rsqrtf(d) : 0.f;
            facc[t] = r;
            int n = b * 256 + t;
            if (n < N_NODES) dis[n] = r;
        }
        __syncthreads();
        for (int idx = t; idx < 8192; idx += 512) {   // x-cast + xs from one x load
            int nl = idx >> 5, q = idx & 31;
            int n = b * 256 + nl;
            if (n < N_NODES) {
                float2 xv = ((const float2*)x)[n * 32 + q];
                float r = facc[nl];
                abuf[n * 96 + q] = packbf2(xv.x, xv.y);       // plain x bf16
                xs[n * 32 + q] = packbf2(r * xv.x, r * xv.y); // dis*x bf16
            }
        }
    }
}

// ---- prop: one wave per node; halves handle alternating edges; u32 rw ----
// mode 0: tx1 = -dis*sum(w*xs[row]); write abuf tx1 + t1s = dis*tx1
// mode 1: tx2 = 2*(-dis*sum(w*t1s[row])) - x(fp32); write abuf tx2
__global__ __launch_bounds__(256) void k_prop(
    const int* __restrict__ off, const unsigned* __restrict__ rw,
    const unsigned* __restrict__ xsrc, const float* __restrict__ dis,
    const float* __restrict__ xf, unsigned* __restrict__ abuf,
    unsigned* __restrict__ t1s, int mode) {
    int node = (blockIdx.x * 256 + threadIdx.x) >> 6;
    if (node >= N_NODES) return;
    int lane = threadIdx.x & 63, h = lane >> 5, q = lane & 31;
    int b = off[node], end = off[node + 1];
    float di = dis[node];
    float acc0 = 0.f, acc1 = 0.f;
    for (; b + 7 < end; b += 8) {
        unsigned v0 = rw[b + h], v1 = rw[b + h + 2], v2 = rw[b + h + 4], v3 = rw[b + h + 6];
        unsigned u0 = xsrc[(v0 & 0xFFFFu) * 32 + q];
        unsigned u1 = xsrc[(v1 & 0xFFFFu) * 32 + q];
        unsigned u2 = xsrc[(v2 & 0xFFFFu) * 32 + q];
        unsigned u3 = xsrc[(v3 & 0xFFFFu) * 32 + q];
        float a0 = bfhi(v0), a1 = bfhi(v1), a2 = bfhi(v2), a3 = bfhi(v3);
        acc0 += a0 * bflo(u0) + a1 * bflo(u1) + a2 * bflo(u2) + a3 * bflo(u3);
        acc1 += a0 * bfhi(u0) + a1 * bfhi(u1) + a2 * bfhi(u2) + a3 * bfhi(u3);
    }
    for (; b + 1 < end; b += 2) {
        unsigned v = rw[b + h];
        unsigned u = xsrc[(v & 0xFFFFu) * 32 + q];
        float a = bfhi(v);
        acc0 += a * bflo(u); acc1 += a * bfhi(u);
    }
    if (b < end && h == 0) {
        unsigned v = rw[b];
        unsigned u = xsrc[(v & 0xFFFFu) * 32 + q];
        float a = bfhi(v);
        acc0 += a * bflo(u); acc1 += a * bfhi(u);
    }
    acc0 += __shfl_xor(acc0, 32, 64);
    acc1 += __shfl_xor(acc1, 32, 64);
    if (h == 0) {
        float t0 = -di * acc0, t1v = -di * acc1;
        if (mode == 0) {
            abuf[node * 96 + 32 + q] = packbf2(t0, t1v);
            t1s[node * 32 + q] = packbf2(di * t0, di * t1v);
        } else {
            float2 xv = ((const float2*)xf)[node * 32 + q];
            abuf[node * 96 + 64 + q] = packbf2(2.f * t0 - xv.x, 2.f * t1v - xv.y);
        }
    }
}

// ---- MFMA GEMM [50048x192]@[192x128] + GRU combine + head (2 tiles/block) ----
__global__ __launch_bounds__(256) void k_gemm(
    const ushort_t* __restrict__ ab, const ushort_t* __restrict__ pbuf,
    const float* __restrict__ bxz, const float* __restrict__ bhz,
    const float* __restrict__ bxh, const float* __restrict__ bhh,
    const float* __restrict__ Wlin, const float* __restrict__ blin,
    float2* __restrict__ out) {
    __shared__ ushort_t bsh[24576];
    int tid = threadIdx.x;
    {
        uint4* s4 = (uint4*)bsh;
        const uint4* g4 = (const uint4*)pbuf;
        for (int i = tid; i < 3072; i += 256) s4[i] = g4[i];
    }
    __syncthreads();

    int wave = tid >> 6, lane = tid & 63;
    int quad = lane >> 4, m = lane & 15;

    float bzv[4], bhv[4], wl0[4], wl1[4];
#pragma unroll
    for (int c = 0; c < 4; ++c) {
        int col = c * 16 + m;
        bzv[c] = bxz[col] + bhz[col];
        bhv[c] = bxh[col] + bhh[col];
        wl0[c] = Wlin[2 * col];
        wl1[c] = Wlin[2 * col + 1];
    }
    float bl0 = blin[0], bl1 = blin[1];

    for (int tile = 0; tile < 2; ++tile) {
        int n0 = (blockIdx.x * 2 + tile) * 64;
        int arow = n0 + wave * 16 + m;
        const ushort_t* ap = ab + (size_t)arow * 192 + quad * 8;

        f32x4 acc[8];
#pragma unroll
        for (int c = 0; c < 8; ++c) acc[c] = (f32x4){0.f, 0.f, 0.f, 0.f};
#pragma unroll
        for (int s = 0; s < 6; ++s) {
            bf16x8 af = *(const bf16x8*)(ap + s * 32);
#pragma unroll
            for (int c = 0; c < 8; ++c) {
                bf16x8 bfr = *(const bf16x8*)(bsh + ((c * 6 + s) * 64 + lane) * 8);
                acc[c] = __builtin_amdgcn_mfma_f32_16x16x32_bf16(af, bfr, acc[c], 0, 0, 0);
            }
        }
#pragma unroll
        for (int i = 0; i < 4; ++i) {
            float p0 = 0.f, p1 = 0.f;
#pragma unroll
            for (int c = 0; c < 4; ++c) {
                float z  = fsigmoid(acc[c][i] + bzv[c]);
                float ht = ftanh(acc[c + 4][i] + bhv[c]);
                float t  = ftanh((1.f - z) * ht);
                p0 += t * wl0[c];
                p1 += t * wl1[c];
            }
            for (int o = 1; o <= 8; o <<= 1) {
                p0 += __shfl_xor(p0, o, 64);
                p1 += __shfl_xor(p1, o, 64);
            }
            int g = n0 + wave * 16 + quad * 4 + i;
            if (m == 0 && g < N_NODES)
                out[g] = make_float2(fsigmoid(p0 + bl0), fsigmoid(p1 + bl1));
        }
    }
}

extern "C" void kernel_launch(void* const* d_in, const int* in_sizes, int n_in,
                              void* d_out, int out_size, void* d_ws, size_t ws_size,
                              hipStream_t stream) {
    const float* x    = (const float*)d_in[0];
    const int*   ei   = (const int*)d_in[1];
    const float* ew   = (const float*)d_in[2];
    const float* Wxz  = (const float*)d_in[3];
    const float* bxz  = (const float*)d_in[4];
    const float* bhz  = (const float*)d_in[6];
    const float* Wxh  = (const float*)d_in[11];
    const float* bxh  = (const float*)d_in[12];
    const float* bhh  = (const float*)d_in[14];
    const float* Wlin = (const float*)d_in[15];
    const float* blin = (const float*)d_in[16];

    float*    ws    = (float*)d_ws;
    unsigned* gcur  = (unsigned*)(ws + GCUR_O);
    float*    dis   = ws + DIS_O;
    int*      off   = (int*)(ws + OFF_O);
    u64*      cslot = (u64*)(ws + CSLOT_O);
    unsigned* rslot = (unsigned*)(ws + RSLOT_O);
    unsigned* rw    = (unsigned*)(ws + RW_O);
    unsigned* abuf  = (unsigned*)(ws + ABUF_O);
    ushort_t* pbuf  = (ushort_t*)(ws + PBUF_O);
    unsigned* xs    = (unsigned*)(ws + XS_O);    // own region (no cslot alias)
    unsigned* t1s   = (unsigned*)(ws + T1S_O);   // aliases rslot (safe)

    hipMemsetAsync(d_ws, 0, 512 * 4, stream);    // just the cursors

    k1<<<NB1 + 1, 512, 0, stream>>>(ei, ew, Wxz, Wxh, gcur, cslot, rslot, pbuf);
    k2<<<2 * NBKT, 512, 0, stream>>>(x, gcur, cslot, rslot, dis, off, rw, abuf, xs);
    k_prop<<<12500, 256, 0, stream>>>(off, rw, xs, dis, x, abuf, t1s, 0);
    k_prop<<<12500, 256, 0, stream>>>(off, rw, t1s, dis, x, abuf, abuf, 1);
    k_gemm<<<391, 256, 0, stream>>>((const ushort_t*)abuf, pbuf, bxz, bhz, bxh, bhh,
                                    Wlin, blin, (float2*)d_out);
}